// Round 3
// baseline (21902.411 us; speedup 1.0000x reference)
//
#include <hip/hip_runtime.h>
#include <hip/hip_bf16.h>

static constexpr int T_ = 512, B_ = 128, DIM_ = 512, H_ = 1024, OUT_ = 512;
static constexpr size_t BH = (size_t)B_ * H_;

__global__ void copy_h0_kernel(const float* __restrict__ h0, float* __restrict__ out) {
    int i = blockIdx.x * blockDim.x + threadIdx.x;
    if (i < B_ * H_) out[i] = h0[i];
}

// C[M,N] = act( A[M,K] @ W[N,K]^T + biases (+ C_staged) )
// NB: 0=none, 1=+b1[c], 2=+b1[c]+b2[c]
// ADD: add the value already in outp (staged pre-activation; same thread RMW)
// ACT: 0=id, 1=tanh, 2=sigmoid
template<int BM, int BN, int BK, int TM, int TN, int NB, bool ADD, int ACT>
__launch_bounds__((BM/TM)*(BN/TN))
__global__ void gemm_kernel(const float* __restrict__ A, const float* __restrict__ W,
                            const float* __restrict__ b1, const float* __restrict__ b2,
                            float* __restrict__ outp, int M, int N, int K)
{
    constexpr int NT = (BM/TM)*(BN/TN);
    __shared__ float As[BK][BM+4];
    __shared__ float Ws[BK][BN+4];
    const int tid  = threadIdx.x;
    const int col0 = blockIdx.x * BN;
    const int row0 = blockIdx.y * BM;
    const int tx = tid % (BN/TN);
    const int ty = tid / (BN/TN);
    const int n0 = tx * TN, m0 = ty * TM;

    float acc[TM][TN];
    #pragma unroll
    for (int i = 0; i < TM; ++i)
        #pragma unroll
        for (int j = 0; j < TN; ++j) acc[i][j] = 0.f;

    for (int k0 = 0; k0 < K; k0 += BK) {
        for (int i = tid; i < BM*BK/4; i += NT) {
            const int r  = i / (BK/4);
            const int kc = (i % (BK/4)) * 4;
            const float* s = A + (size_t)(row0 + r) * K + (k0 + kc);
            #pragma unroll
            for (int j = 0; j < 4; ++j) As[kc + j][r] = s[j];
        }
        for (int i = tid; i < BN*BK/4; i += NT) {
            const int r  = i / (BK/4);
            const int kc = (i % (BK/4)) * 4;
            const float* s = W + (size_t)(col0 + r) * K + (k0 + kc);
            #pragma unroll
            for (int j = 0; j < 4; ++j) Ws[kc + j][r] = s[j];
        }
        __syncthreads();
        #pragma unroll
        for (int k = 0; k < BK; ++k) {
            float av[TM], wv[TN];
            #pragma unroll
            for (int i = 0; i < TM; ++i) av[i] = As[k][m0 + i];
            #pragma unroll
            for (int j = 0; j < TN; ++j) wv[j] = Ws[k][n0 + j];
            #pragma unroll
            for (int i = 0; i < TM; ++i)
                #pragma unroll
                for (int j = 0; j < TN; ++j) acc[i][j] = fmaf(av[i], wv[j], acc[i][j]);
        }
        __syncthreads();
    }

    #pragma unroll
    for (int i = 0; i < TM; ++i) {
        const size_t r = (size_t)(row0 + m0 + i);
        #pragma unroll
        for (int j = 0; j < TN; ++j) {
            const int c = col0 + n0 + j;
            float v = acc[i][j];
            if constexpr (NB >= 1) v += b1[c];
            if constexpr (NB >= 2) v += b2[c];
            if constexpr (ADD)     v += outp[r * (size_t)N + c];
            if constexpr (ACT == 1) v = tanhf(v);
            else if constexpr (ACT == 2) v = 1.0f / (1.0f + expf(-v));
            outp[r * (size_t)N + c] = v;
        }
    }
}

extern "C" void kernel_launch(void* const* d_in, const int* in_sizes, int n_in,
                              void* d_out, int out_size, void* d_ws, size_t ws_size,
                              hipStream_t stream)
{
    const float* x    = (const float*)d_in[0];
    const float* h0   = (const float*)d_in[1];
    const float* Wx_w = (const float*)d_in[2];
    const float* Wx_b = (const float*)d_in[3];
    const float* Wh_w = (const float*)d_in[4];
    const float* Wh_b = (const float*)d_in[5];
    const float* Wo_w = (const float*)d_in[6];
    const float* Wo_b = (const float*)d_in[7];

    float* out   = (float*)d_out;
    float* all_h = out;                              // [T+1][B][H]  (f32!)
    float* all_y = out + (size_t)(T_ + 1) * BH;      // [T][B][OUT]
    float* last  = all_y + (size_t)T_ * B_ * OUT_;   // [B][OUT]

    // all_h[0] = h0
    copy_h0_kernel<<<dim3((B_*H_ + 255)/256), dim3(256), 0, stream>>>(h0, all_h);

    // Stage xproj = x@Wx^T + Wx_b + Wh_b (f32 pre-activations) into all_h[1..T]
    gemm_kernel<64, 64, 32, 4, 4, 2, false, 0>
        <<<dim3(H_/64, (T_*B_)/64), dim3(256), 0, stream>>>(
            x, Wx_w, Wx_b, Wh_b, all_h + BH, T_*B_, H_, DIM_);

    // Recurrence in place over the staged slot:
    // all_h[t+1] = tanh(all_h[t] @ Wh^T + staged_xp)
    for (int t = 0; t < T_; ++t) {
        gemm_kernel<16, 64, 32, 1, 4, 0, true, 1>
            <<<dim3(H_/64, B_/16), dim3(256), 0, stream>>>(
                all_h + (size_t)t * BH, Wh_w, nullptr, nullptr,
                all_h + (size_t)(t + 1) * BH, B_, H_, H_);
    }

    // all_y = sigmoid(hs @ Wo^T + Wo_b), hs = all_h[1..T] (f32)
    gemm_kernel<64, 64, 32, 4, 4, 1, false, 2>
        <<<dim3(OUT_/64, (T_*B_)/64), dim3(256), 0, stream>>>(
            all_h + BH, Wo_w, Wo_b, nullptr, all_y, T_*B_, OUT_, H_);

    // last_logits = h_T @ Wo^T + Wo_b  (no activation), h_T = all_h[T] (f32)
    gemm_kernel<16, 64, 32, 1, 4, 1, false, 0>
        <<<dim3(OUT_/64, B_/16), dim3(256), 0, stream>>>(
            all_h + (size_t)T_ * BH, Wo_w, Wo_b, nullptr, last, B_, OUT_, H_);
}

// Round 4
// 8580.994 us; speedup vs baseline: 2.5524x; 2.5524x over previous
//
#include <hip/hip_runtime.h>
#include <hip/hip_bf16.h>

static constexpr int T_ = 512, B_ = 128, DIM_ = 512, H_ = 1024, OUT_ = 512;
static constexpr size_t BH = (size_t)B_ * H_;

__global__ void copy_h0_kernel(const float* __restrict__ h0, float* __restrict__ out) {
    int i = blockIdx.x * blockDim.x + threadIdx.x;
    if (i < B_ * H_) out[i] = h0[i];
}

// C[M,N] = act( A[M,K] @ W[N,K]^T + biases )
// NB: 0=none, 1=+b1[c], 2=+b1[c]+b2[c];  ACT: 0=id, 1=tanh, 2=sigmoid
template<int BM, int BN, int BK, int TM, int TN, int NB, int ACT>
__launch_bounds__((BM/TM)*(BN/TN))
__global__ void gemm_kernel(const float* __restrict__ A, const float* __restrict__ W,
                            const float* __restrict__ b1, const float* __restrict__ b2,
                            float* __restrict__ outp, int M, int N, int K)
{
    constexpr int NT = (BM/TM)*(BN/TN);
    __shared__ float As[BK][BM+4];
    __shared__ float Ws[BK][BN+4];
    const int tid  = threadIdx.x;
    const int col0 = blockIdx.x * BN;
    const int row0 = blockIdx.y * BM;
    const int tx = tid % (BN/TN);
    const int ty = tid / (BN/TN);
    const int n0 = tx * TN, m0 = ty * TM;

    float acc[TM][TN];
    #pragma unroll
    for (int i = 0; i < TM; ++i)
        #pragma unroll
        for (int j = 0; j < TN; ++j) acc[i][j] = 0.f;

    for (int k0 = 0; k0 < K; k0 += BK) {
        for (int i = tid; i < BM*BK/4; i += NT) {
            const int r  = i / (BK/4);
            const int kc = (i % (BK/4)) * 4;
            const float* s = A + (size_t)(row0 + r) * K + (k0 + kc);
            #pragma unroll
            for (int j = 0; j < 4; ++j) As[kc + j][r] = s[j];
        }
        for (int i = tid; i < BN*BK/4; i += NT) {
            const int r  = i / (BK/4);
            const int kc = (i % (BK/4)) * 4;
            const float* s = W + (size_t)(col0 + r) * K + (k0 + kc);
            #pragma unroll
            for (int j = 0; j < 4; ++j) Ws[kc + j][r] = s[j];
        }
        __syncthreads();
        #pragma unroll
        for (int k = 0; k < BK; ++k) {
            float av[TM], wv[TN];
            #pragma unroll
            for (int i = 0; i < TM; ++i) av[i] = As[k][m0 + i];
            #pragma unroll
            for (int j = 0; j < TN; ++j) wv[j] = Ws[k][n0 + j];
            #pragma unroll
            for (int i = 0; i < TM; ++i)
                #pragma unroll
                for (int j = 0; j < TN; ++j) acc[i][j] = fmaf(av[i], wv[j], acc[i][j]);
        }
        __syncthreads();
    }

    #pragma unroll
    for (int i = 0; i < TM; ++i) {
        const size_t r = (size_t)(row0 + m0 + i);
        #pragma unroll
        for (int j = 0; j < TN; ++j) {
            const int c = col0 + n0 + j;
            float v = acc[i][j];
            if constexpr (NB >= 1) v += b1[c];
            if constexpr (NB >= 2) v += b2[c];
            if constexpr (ACT == 1) v = tanhf(v);
            else if constexpr (ACT == 2) v = 1.0f / (1.0f + expf(-v));
            outp[r * (size_t)N + c] = v;
        }
    }
}

// One recurrence step: hout = tanh(hsrc @ Wh^T + hout_staged_xp), all f32.
// Block: 64 rows x 8 cols. 4 waves, each owns a k-quarter (256 k), lane = row.
// Wh slice (8 cols x 1024 k = 32KB) staged in LDS once; read as wave-uniform
// broadcast float4. h read per-lane from global (L1/L2-hot). Cross-wave
// reduction through 8KB LDS, then fused xp-add + tanh + store (same-thread RMW).
__launch_bounds__(256)
__global__ void step_v2(const float* __restrict__ hsrc, const float* __restrict__ Wh,
                        float* __restrict__ hout)
{
    __shared__ float WhS[8 * 1024];     // [col][k]
    __shared__ float red[4][64][8];     // [wave][row][col]

    const int tid  = threadIdx.x;
    const int c0   = blockIdx.x * 8;
    const int r0   = blockIdx.y * 64;
    const int w    = tid >> 6;
    const int lane = tid & 63;

    // Stage Wh slice: row j of slice = Wh[(c0+j)*H + 0..1023]; thread i moves float4 #i.
    {
        const float4* src;
        float4* dst = (float4*)WhS;
        #pragma unroll
        for (int j = 0; j < 8; ++j) {
            src = (const float4*)(Wh + (size_t)(c0 + j) * H_);
            dst[j * 256 + tid] = src[tid];
        }
    }
    __syncthreads();

    // Compute partial dot over this wave's k-quarter.
    const float4* hrow = (const float4*)(hsrc + (size_t)(r0 + lane) * H_ + w * 256);
    float acc[8] = {0.f,0.f,0.f,0.f,0.f,0.f,0.f,0.f};

    #pragma unroll 2
    for (int kg = 0; kg < 64; ++kg) {
        const float4 hv = hrow[kg];
        #pragma unroll
        for (int c = 0; c < 8; ++c) {
            const float4 wv = ((const float4*)(WhS + c * 1024))[w * 64 + kg];
            acc[c] = fmaf(hv.x, wv.x, acc[c]);
            acc[c] = fmaf(hv.y, wv.y, acc[c]);
            acc[c] = fmaf(hv.z, wv.z, acc[c]);
            acc[c] = fmaf(hv.w, wv.w, acc[c]);
        }
    }

    *(float4*)&red[w][lane][0] = make_float4(acc[0], acc[1], acc[2], acc[3]);
    *(float4*)&red[w][lane][4] = make_float4(acc[4], acc[5], acc[6], acc[7]);
    __syncthreads();

    // Final: 2 cells per thread; sum 4 partials, add staged xp, tanh, store.
    const int r  = tid >> 2;
    const int c2 = (tid & 3) * 2;
    #pragma unroll
    for (int u = 0; u < 2; ++u) {
        const int c = c2 + u;
        const float s = red[0][r][c] + red[1][r][c] + red[2][r][c] + red[3][r][c];
        const size_t idx = (size_t)(r0 + r) * H_ + (c0 + c);
        hout[idx] = tanhf(s + hout[idx]);
    }
}

extern "C" void kernel_launch(void* const* d_in, const int* in_sizes, int n_in,
                              void* d_out, int out_size, void* d_ws, size_t ws_size,
                              hipStream_t stream)
{
    const float* x    = (const float*)d_in[0];
    const float* h0   = (const float*)d_in[1];
    const float* Wx_w = (const float*)d_in[2];
    const float* Wx_b = (const float*)d_in[3];
    const float* Wh_w = (const float*)d_in[4];
    const float* Wh_b = (const float*)d_in[5];
    const float* Wo_w = (const float*)d_in[6];
    const float* Wo_b = (const float*)d_in[7];

    float* out   = (float*)d_out;
    float* all_h = out;                              // [T+1][B][H]
    float* all_y = out + (size_t)(T_ + 1) * BH;      // [T][B][OUT]
    float* last  = all_y + (size_t)T_ * B_ * OUT_;   // [B][OUT]

    // all_h[0] = h0
    copy_h0_kernel<<<dim3((B_*H_ + 255)/256), dim3(256), 0, stream>>>(h0, all_h);

    // Stage xproj = x@Wx^T + Wx_b + Wh_b (f32 pre-activations) into all_h[1..T]
    gemm_kernel<64, 64, 32, 4, 4, 2, 0>
        <<<dim3(H_/64, (T_*B_)/64), dim3(256), 0, stream>>>(
            x, Wx_w, Wx_b, Wh_b, all_h + BH, T_*B_, H_, DIM_);

    // Recurrence in place over the staged slot.
    for (int t = 0; t < T_; ++t) {
        step_v2<<<dim3(H_/8, B_/64), dim3(256), 0, stream>>>(
            all_h + (size_t)t * BH, Wh_w, all_h + (size_t)(t + 1) * BH);
    }

    // all_y = sigmoid(hs @ Wo^T + Wo_b), hs = all_h[1..T]
    gemm_kernel<64, 64, 32, 4, 4, 1, 2>
        <<<dim3(OUT_/64, (T_*B_)/64), dim3(256), 0, stream>>>(
            all_h + BH, Wo_w, Wo_b, nullptr, all_y, T_*B_, OUT_, H_);

    // last_logits = h_T @ Wo^T + Wo_b
    gemm_kernel<16, 64, 32, 1, 4, 1, 0>
        <<<dim3(OUT_/64, B_/16), dim3(256), 0, stream>>>(
            all_h + (size_t)T_ * BH, Wo_w, Wo_b, nullptr, last, B_, OUT_, H_);
}